// Round 1
// 380.209 us; speedup vs baseline: 1.1507x; 1.1507x over previous
//
#include <hip/hip_runtime.h>

typedef __bf16 bf16_t;
typedef __bf16 bf16x8 __attribute__((ext_vector_type(8)));
typedef float f32x4 __attribute__((ext_vector_type(4)));
typedef unsigned short ushort_t;

#define MFMA_16x16x32(a, b, c) __builtin_amdgcn_mfma_f32_16x16x32_bf16((a), (b), (c), 0, 0, 0)

// async global->LDS, 16B per lane. LDS dest must be wave-uniform; HW adds lane*16.
__device__ __forceinline__ void async_ld16(const void* gptr, void* lptr) {
  typedef __attribute__((address_space(1))) const unsigned int as1_t;
  typedef __attribute__((address_space(3))) unsigned int as3_t;
  __builtin_amdgcn_global_load_lds((as1_t*)(unsigned long long)gptr,
                                   (as3_t*)(unsigned int)(unsigned long long)lptr,
                                   16, 0, 0);
}

// ---------------------------------------------------------------------------
// Input-dtype detector (f32-read-as-bf16 has ~47% wild exponents in low halves).
// ---------------------------------------------------------------------------
__global__ void detect_dtype(const ushort_t* __restrict__ x, int* __restrict__ flag) {
  __shared__ int cnt[256];
  int c = 0;
#pragma unroll
  for (int i = 0; i < 16; ++i) {
    const ushort_t u = x[threadIdx.x * 16 + i];
    const int e = (u >> 7) & 0xFF;
    if ((u & 0x7FFF) != 0 && (e < 0x3A || e > 0xC0)) ++c;
  }
  cnt[threadIdx.x] = c;
  __syncthreads();
  if (threadIdx.x == 0) {
    int t = 0;
    for (int i = 0; i < 256; ++i) t += cnt[i];
    *flag = (t > 512) ? 1 : 0;
  }
}

// ---------------------------------------------------------------------------
// Normalize input to bf16 (flag==1: f32 src; else 16B copy). n8 = elems/8.
// ---------------------------------------------------------------------------
__global__ __launch_bounds__(256) void convert_to_bf16(const void* __restrict__ src,
                                                       bf16_t* __restrict__ dst, int n8,
                                                       const int* __restrict__ flag) {
  const int isF32 = *flag;
  int i = blockIdx.x * 256 + threadIdx.x;
  const int stride = gridDim.x * 256;
  if (isF32) {
    const float4* s = (const float4*)src;
    for (; i < n8; i += stride) {
      const float4 a = s[(size_t)i * 2];
      const float4 b = s[(size_t)i * 2 + 1];
      bf16x8 o;
      o[0] = (bf16_t)a.x; o[1] = (bf16_t)a.y; o[2] = (bf16_t)a.z; o[3] = (bf16_t)a.w;
      o[4] = (bf16_t)b.x; o[5] = (bf16_t)b.y; o[6] = (bf16_t)b.z; o[7] = (bf16_t)b.w;
      *(bf16x8*)(dst + (size_t)i * 8) = o;
    }
  } else {
    const uint4* s = (const uint4*)src;
    for (; i < n8; i += stride) ((uint4*)dst)[i] = s[i];
  }
}

// ---------------------------------------------------------------------------
// 64x64 bf16 transpose: out[c][r] = in[r][c].  R,C multiples of 64.
// ---------------------------------------------------------------------------
__global__ __launch_bounds__(256) void transpose_b16(const ushort_t* __restrict__ in,
                                                     ushort_t* __restrict__ out,
                                                     int R, int C) {
  __shared__ alignas(16) ushort_t t[64 * 72];
  const int tid = threadIdx.x;
  const int c0 = blockIdx.x * 64;
  const int r0 = blockIdx.y * 64;
#pragma unroll
  for (int it = 0; it < 2; ++it) {
    int cid = tid + it * 256;
    int row = cid >> 3, co = (cid & 7) * 8;
    *(uint4*)(t + row * 72 + co) = *(const uint4*)(in + (size_t)(r0 + row) * C + c0 + co);
  }
  __syncthreads();
#pragma unroll
  for (int it = 0; it < 2; ++it) {
    int cid = tid + it * 256;
    int orow = cid >> 3, ko = (cid & 7) * 8;
    uint4 u;
    ushort_t* tp = (ushort_t*)&u;
#pragma unroll
    for (int j = 0; j < 8; ++j) tp[j] = t[(ko + j) * 72 + orow];
    *(uint4*)(out + (size_t)(c0 + orow) * R + r0 + ko) = u;
  }
}

// ---------------------------------------------------------------------------
// Batched V transpose: qkv[b*4096+l][2048+h*64+d] -> vT[((b*16+h)*64+d)*4096+l]
// grid (64 l-tiles, 64 bh). Fully coalesced 16B both sides.
// ---------------------------------------------------------------------------
__global__ __launch_bounds__(256) void transpose_v(const ushort_t* __restrict__ qkv,
                                                   ushort_t* __restrict__ vT) {
  __shared__ alignas(16) ushort_t t[64 * 72];
  const int tid = threadIdx.x;
  const int l0 = blockIdx.x * 64;
  const int bh = blockIdx.y;
  const int b = bh >> 4, h = bh & 15;
  const ushort_t* src = qkv + ((size_t)(b * 4096 + l0)) * 3072 + 2048 + h * 64;
#pragma unroll
  for (int it = 0; it < 2; ++it) {
    int cid = tid + it * 256;
    int row = cid >> 3, co = (cid & 7) * 8;
    *(uint4*)(t + row * 72 + co) = *(const uint4*)(src + (size_t)row * 3072 + co);
  }
  __syncthreads();
  ushort_t* dst = vT + ((size_t)bh * 64) * 4096 + l0;
#pragma unroll
  for (int it = 0; it < 2; ++it) {
    int cid = tid + it * 256;
    int d = cid >> 3, ko = (cid & 7) * 8;
    uint4 u;
    ushort_t* tp = (ushort_t*)&u;
#pragma unroll
    for (int j = 0; j < 8; ++j) tp[j] = t[(ko + j) * 72 + d];
    *(uint4*)(dst + (size_t)d * 4096 + ko) = u;
  }
}

// ---------------------------------------------------------------------------
// GEMM: C[M][N] = A[M][K] * Bt[N][K]^T.  256x256 tile, BK=64, 8 waves (2Mx4N),
// 512 threads, 8-phase schedule (T1+T2+T3+T4+T5, m201 template re-derived):
//  - interleaved wave->row mapping: phase (mh,nh) reads exactly A-half[mh],
//    B-half[nh] -> half-tile-granular prefetch works under 2 LDS buffers.
//  - per phase: ds_read frags | issue 1 half-tile global_load_lds | counted
//    vmcnt (never 0 in-loop) | s_barrier | lgkmcnt(0)+sched_barrier |
//    setprio(1) 16xMFMA setprio(0) | s_barrier.
//  - LDS swizzle: linear dest (global_load_lds requires it) + inverse-swizzled
//    global source chunk (j ^ (row&7)) + same XOR on ds_read (rule #21).
// vmcnt ledger (per-wave instrs, 2 per half-tile; stage order A-lo,B-lo,B-hi,A-hi):
//  P1 wait(4) -> B-hi(t) done (needed P2); P2 wait(4) -> A-hi(t) (needed P3);
//  P3 wait(6) no-op; P4 wait(4) -> A-lo,B-lo(t+1) (needed next P1).
// ---------------------------------------------------------------------------
__global__ __launch_bounds__(512) void gemm_bf16(const bf16_t* __restrict__ A, int lda,
                                                 const bf16_t* __restrict__ Bt,
                                                 void* __restrict__ Cout, int N_out,
                                                 int K, const int* __restrict__ flag) {
  __shared__ alignas(16) bf16_t smem[65536];  // 128 KiB: [buf][A 16K | B 16K] elems
  const int tid = threadIdx.x;
  const int wave = tid >> 6;
  const int lane = tid & 63;
  const int l15 = lane & 15;
  const int quad = lane >> 4;
  const int wm = wave >> 2;  // 0..1
  const int wn = wave & 3;   // 0..3

  // XCD-bijective block swizzle (T1); our launches have nwg % 8 == 0.
  int lin = blockIdx.y * gridDim.x + blockIdx.x;
  const int nwg = gridDim.x * gridDim.y;
  if ((nwg & 7) == 0) lin = (lin & 7) * (nwg >> 3) + (lin >> 3);
  const int tn = (lin % gridDim.x) * 256;
  const int tm = (lin / gridDim.x) * 256;

  f32x4 acc[8][4];
#pragma unroll
  for (int i = 0; i < 8; ++i)
#pragma unroll
    for (int j = 0; j < 4; ++j) acc[i][j] = (f32x4){0.f, 0.f, 0.f, 0.f};

  // staging: thread t covers (row = t>>3, chunk = t&7) of a 64-row call-block;
  // global chunk is pre-swizzled so linear LDS ends up XOR-swizzled.
  const int r_st = tid >> 3;
  const int jg8 = ((tid & 7) ^ (r_st & 7)) * 8;
  const int wofs = wave * 512;  // wave-uniform LDS base (elems); HW adds lane*16B

  // fragment-read constants; chunk' = (ks*4|quad) ^ (row&7), row&7 == l15&7
  const int rowA = wm * 16 + l15;
  const int rowB = wn * 16 + l15;
  const int sw = l15 & 7;
  const int c0 = (quad ^ sw) * 8;
  const int c1 = ((quad | 4) ^ sw) * 8;

  const int NT = K >> 6;

#define STAGE_HALF(G, ldg, grow0, kk, ldsbase)                              \
  do {                                                                      \
    const bf16_t* _g = (G) + (size_t)((grow0) + r_st) * (ldg) + (kk) + jg8; \
    async_ld16(_g, &smem[(ldsbase) + wofs]);                                \
    async_ld16(_g + (size_t)64 * (ldg), &smem[(ldsbase) + 4096 + wofs]);    \
  } while (0)

#define READ_A(mh)                                                \
  do {                                                            \
    _Pragma("unroll") for (int q = 0; q < 4; ++q) {               \
      const int off = bufA + (((mh)*128 + q * 32 + rowA) << 6);   \
      a_[q][0] = *(const bf16x8*)&smem[off + c0];                 \
      a_[q][1] = *(const bf16x8*)&smem[off + c1];                 \
    }                                                             \
  } while (0)

#define READ_B(nh)                                                \
  do {                                                            \
    _Pragma("unroll") for (int jn = 0; jn < 2; ++jn) {            \
      const int off = bufB + (((nh)*128 + jn * 64 + rowB) << 6);  \
      b_[jn][0] = *(const bf16x8*)&smem[off + c0];                \
      b_[jn][1] = *(const bf16x8*)&smem[off + c1];                \
    }                                                             \
  } while (0)

#define DO_MFMA(mh, nh)                                                      \
  do {                                                                       \
    _Pragma("unroll") for (int q = 0; q < 4; ++q)                            \
        _Pragma("unroll") for (int jn = 0; jn < 2; ++jn) {                   \
      acc[(mh)*4 + q][(nh)*2 + jn] =                                         \
          MFMA_16x16x32(a_[q][0], b_[jn][0], acc[(mh)*4 + q][(nh)*2 + jn]);  \
      acc[(mh)*4 + q][(nh)*2 + jn] =                                         \
          MFMA_16x16x32(a_[q][1], b_[jn][1], acc[(mh)*4 + q][(nh)*2 + jn]);  \
    }                                                                        \
  } while (0)

#define PHASE_MID(VMC)                                     \
  asm volatile("s_waitcnt vmcnt(" VMC ")" ::: "memory");   \
  __builtin_amdgcn_s_barrier();                            \
  asm volatile("s_waitcnt lgkmcnt(0)" ::: "memory");       \
  __builtin_amdgcn_sched_barrier(0);                       \
  __builtin_amdgcn_s_setprio(1)

#define PHASE_END()               \
  __builtin_amdgcn_s_setprio(0);  \
  __builtin_amdgcn_s_barrier();   \
  __builtin_amdgcn_sched_barrier(0)

  // prologue: stage K-tile 0 into buffer 0; wait until A-lo,B-lo resident.
  STAGE_HALF(A, lda, tm, 0, 0);
  STAGE_HALF(Bt, K, tn, 0, 16384);
  STAGE_HALF(Bt, K, tn + 128, 0, 16384 + 8192);
  STAGE_HALF(A, lda, tm + 128, 0, 8192);
  asm volatile("s_waitcnt vmcnt(4)" ::: "memory");
  __builtin_amdgcn_s_barrier();

  bf16x8 a_[4][2], b_[2][2];
  int bufA = 0;
  for (int t = 0; t < NT; ++t) {
    const int bufB = bufA + 16384;
    const int sA = bufA ^ 32768;  // stage target = other buffer
    const int sB = sA + 16384;
    int kst = (t + 1) << 6;
    if (kst == K) kst = 0;  // wrapped prefetch on last tile (data never read)

    // P1: quadrant (mh0,nh0); stage A-lo(t+1)
    READ_A(0);
    READ_B(0);
    STAGE_HALF(A, lda, tm, kst, sA);
    PHASE_MID("4");
    DO_MFMA(0, 0);
    PHASE_END();

    // P2: (mh0,nh1); stage B-lo(t+1)
    READ_B(1);
    STAGE_HALF(Bt, K, tn, kst, sB);
    PHASE_MID("4");
    DO_MFMA(0, 1);
    PHASE_END();

    // P3: (mh1,nh1); stage B-hi(t+1)
    READ_A(1);
    STAGE_HALF(Bt, K, tn + 128, kst, sB + 8192);
    PHASE_MID("6");
    DO_MFMA(1, 1);
    PHASE_END();

    // P4: (mh1,nh0); stage A-hi(t+1)
    READ_B(0);
    STAGE_HALF(A, lda, tm + 128, kst, sA + 8192);
    PHASE_MID("4");
    DO_MFMA(1, 0);
    PHASE_END();

    bufA ^= 32768;
  }

  // drain wrapped prefetch before reusing smem for the epilogue.
  asm volatile("s_waitcnt vmcnt(0)" ::: "memory");
  __syncthreads();

  const int isF32 = flag ? *flag : 0;
  if (isF32) {
#pragma unroll
    for (int f = 0; f < 8; ++f) {
      const int m0 = tm + (f >> 2) * 128 + (f & 3) * 32 + wm * 16 + quad * 4;
#pragma unroll
      for (int nidx = 0; nidx < 4; ++nidx) {
        const int col = tn + (nidx >> 1) * 128 + (nidx & 1) * 64 + wn * 16 + l15;
        float* cp = (float*)Cout + (size_t)m0 * N_out + col;
#pragma unroll
        for (int r = 0; r < 4; ++r) cp[(size_t)r * N_out] = acc[f][nidx][r];
      }
    }
  } else {
    // per-wave 16x72 staging tile; shuffle C-layout -> 16B/lane coalesced stores
    bf16_t* stg = smem + wave * 1152;
#pragma unroll
    for (int f = 0; f < 8; ++f) {
#pragma unroll
      for (int nidx = 0; nidx < 4; ++nidx)
#pragma unroll
        for (int r = 0; r < 4; ++r)
          stg[(quad * 4 + r) * 72 + nidx * 16 + l15] = (bf16_t)acc[f][nidx][r];
      __asm__ volatile("s_waitcnt lgkmcnt(0)" ::: "memory");
      const int m0 = tm + (f >> 2) * 128 + (f & 3) * 32 + wm * 16;
#pragma unroll
      for (int p = 0; p < 2; ++p) {
        const int idx = lane + p * 64;
        const int row = idx >> 3, c8 = (idx & 7) * 8;
        uint4 u = *(const uint4*)(stg + row * 72 + c8);
        const int col = tn + ((c8 >> 5) << 7) + (((c8 >> 4) & 1) << 6) + wn * 16 + (c8 & 15);
        *(uint4*)((bf16_t*)Cout + (size_t)(m0 + row) * N_out + col) = u;
      }
      __asm__ volatile("s_waitcnt lgkmcnt(0)" ::: "memory");
    }
  }
#undef STAGE_HALF
#undef READ_A
#undef READ_B
#undef DO_MFMA
#undef PHASE_MID
#undef PHASE_END
}

// ---------------------------------------------------------------------------
// Sliding-window attention. One workgroup = 64 queries of one (b,h); 4 waves x
// 16 rows. Window = 5 chunks of 64 keys. qkv: [b*4096+pos][3072] (Q at h*64,
// K at 1024+h*64; O overwrites the Q columns). vT: [b][h][d][4096].
// ---------------------------------------------------------------------------
__global__ __launch_bounds__(256) void attn_swa(bf16_t* qkv, const bf16_t* __restrict__ vT) {
  __shared__ alignas(16) bf16_t k_lds[64 * 72];   // [key][d]
  __shared__ alignas(16) bf16_t vt_lds[64 * 72];  // [d][key]
  __shared__ alignas(16) bf16_t p_lds[4 * 16 * 72];

  const int wg = blockIdx.x;
  const int b = wg >> 10;
  const int h = (wg >> 6) & 15;
  const int qt = wg & 63;
  const int blk = qt >> 2;
  const int wq = qt & 3;
  const int tid = threadIdx.x;
  const int wave = tid >> 6;
  const int lane = tid & 63;
  const int l15 = lane & 15;
  const int quad = lane >> 4;
  const int qw = qt * 64 + wave * 16;

  const size_t qoff = ((size_t)(b * 4096 + qw + l15)) * 3072 + h * 64;
  const bf16x8 qf0 = *(const bf16x8*)(qkv + qoff + quad * 8);
  const bf16x8 qf1 = *(const bf16x8*)(qkv + qoff + 32 + quad * 8);

  f32x4 of[4];
#pragma unroll
  for (int i = 0; i < 4; ++i) of[i] = (f32x4){0.f, 0.f, 0.f, 0.f};
  float m_i[4], l_i[4];
#pragma unroll
  for (int r = 0; r < 4; ++r) {
    m_i[r] = -1e30f;
    l_i[r] = 0.0f;
  }

  const int kb0 = blk * 256 - 256;
  const int kclo = (blk == 0) ? 4 : wq;
  const int kchi = wq + 4;

  for (int kc = kclo; kc <= kchi; ++kc) {
    const int kb = kb0 + kc * 64;
    __syncthreads();
#pragma unroll
    for (int it = 0; it < 2; ++it) {
      int cid = tid + it * 256;
      int row = cid >> 3;
      int co = (cid & 7) * 8;
      *(uint4*)(k_lds + row * 72 + co) =
          *(const uint4*)(qkv + ((size_t)(b * 4096 + kb + row)) * 3072 + 1024 + h * 64 + co);
      *(uint4*)(vt_lds + row * 72 + co) =
          *(const uint4*)(vT + (((size_t)b * 16 + h) * 64 + row) * 4096 + kb + co);
    }
    __syncthreads();

    f32x4 s[4];
#pragma unroll
    for (int nt = 0; nt < 4; ++nt) {
      bf16x8 kf0 = *(const bf16x8*)(k_lds + (nt * 16 + l15) * 72 + quad * 8);
      bf16x8 kf1 = *(const bf16x8*)(k_lds + (nt * 16 + l15) * 72 + 32 + quad * 8);
      f32x4 z = (f32x4){0.f, 0.f, 0.f, 0.f};
      z = MFMA_16x16x32(qf0, kf0, z);
      z = MFMA_16x16x32(qf1, kf1, z);
      s[nt] = z;
    }

    float sv[4][4];
#pragma unroll
    for (int nt = 0; nt < 4; ++nt) {
      const int key = kb + nt * 16 + l15;
#pragma unroll
      for (int r = 0; r < 4; ++r) {
        const int p = qw + quad * 4 + r;
        const bool valid = (key <= p) && (key + 256 > p);
        sv[nt][r] = valid ? s[nt][r] * 0.125f : -1e30f;
      }
    }
    float rm[4];
#pragma unroll
    for (int r = 0; r < 4; ++r)
      rm[r] = fmaxf(fmaxf(sv[0][r], sv[1][r]), fmaxf(sv[2][r], sv[3][r]));
#pragma unroll
    for (int off = 1; off < 16; off <<= 1)
#pragma unroll
      for (int r = 0; r < 4; ++r) rm[r] = fmaxf(rm[r], __shfl_xor(rm[r], off));

    float mn[4], alpha[4];
#pragma unroll
    for (int r = 0; r < 4; ++r) {
      mn[r] = fmaxf(m_i[r], rm[r]);
      alpha[r] = __expf(m_i[r] - mn[r]);
      m_i[r] = mn[r];
    }

    float rs[4] = {0.f, 0.f, 0.f, 0.f};
#pragma unroll
    for (int nt = 0; nt < 4; ++nt)
#pragma unroll
      for (int r = 0; r < 4; ++r) {
        const float pv = (sv[nt][r] > -1e29f) ? __expf(sv[nt][r] - mn[r]) : 0.0f;
        rs[r] += pv;
        p_lds[wave * 1152 + (quad * 4 + r) * 72 + nt * 16 + l15] = (bf16_t)pv;
      }
#pragma unroll
    for (int off = 1; off < 16; off <<= 1)
#pragma unroll
      for (int r = 0; r < 4; ++r) rs[r] += __shfl_xor(rs[r], off);
#pragma unroll
    for (int r = 0; r < 4; ++r) l_i[r] = l_i[r] * alpha[r] + rs[r];
#pragma unroll
    for (int dt = 0; dt < 4; ++dt)
#pragma unroll
      for (int r = 0; r < 4; ++r) of[dt][r] *= alpha[r];

    __syncthreads();

#pragma unroll
    for (int kk = 0; kk < 2; ++kk) {
      bf16x8 pf = *(const bf16x8*)(p_lds + wave * 1152 + l15 * 72 + kk * 32 + quad * 8);
#pragma unroll
      for (int dt = 0; dt < 4; ++dt) {
        bf16x8 vf = *(const bf16x8*)(vt_lds + (dt * 16 + l15) * 72 + kk * 32 + quad * 8);
        of[dt] = MFMA_16x16x32(pf, vf, of[dt]);
      }
    }
  }

  float inv[4];
#pragma unroll
  for (int r = 0; r < 4; ++r) inv[r] = 1.0f / fmaxf(l_i[r], 1e-20f);
  bf16_t* op = qkv + ((size_t)(b * 4096 + qw)) * 3072 + h * 64;  // overwrite Q cols
#pragma unroll
  for (int dt = 0; dt < 4; ++dt)
#pragma unroll
    for (int r = 0; r < 4; ++r)
      op[(size_t)(quad * 4 + r) * 3072 + dt * 16 + l15] = (bf16_t)(of[dt][r] * inv[r]);
}

// ---------------------------------------------------------------------------
extern "C" void kernel_launch(void* const* d_in, const int* in_sizes, int n_in,
                              void* d_out, int out_size, void* d_ws, size_t ws_size,
                              hipStream_t stream) {
  char* ws = (char*)d_ws;
  bf16_t* wTq = (bf16_t*)(ws);                    // [3072][1024]   6,291,456 B
  bf16_t* wTo = (bf16_t*)(ws + 6291456);          // [1024][1024]   2,097,152 B
  bf16_t* qkv = (bf16_t*)(ws + 8388608);          // [16384][3072] 100,663,296 B
  int* flag = (int*)(ws + 109051904);             // 4 B (total 109,051,908 B)

  bf16_t* xb = (bf16_t*)d_out;   // converted x (32 MB), consumed by QKV GEMM
  bf16_t* vTb = (bf16_t*)d_out;  // then vT (32 MB), consumed by attention,
                                 // then final GEMM writes d_out. Stream-ordered.
  bf16_t* tmpq = qkv;            // converted w_qkv, consumed by transpose
  bf16_t* tmpo = qkv + 3145728;  // converted w_out, consumed by transpose

  detect_dtype<<<1, 256, 0, stream>>>((const ushort_t*)d_in[0], flag);
  convert_to_bf16<<<1024, 256, 0, stream>>>(d_in[0], xb, 2097152, flag);
  convert_to_bf16<<<512, 256, 0, stream>>>(d_in[1], tmpq, 393216, flag);
  convert_to_bf16<<<256, 256, 0, stream>>>(d_in[2], tmpo, 131072, flag);
  transpose_b16<<<dim3(48, 16), 256, 0, stream>>>((const ushort_t*)tmpq, (ushort_t*)wTq,
                                                  1024, 3072);
  transpose_b16<<<dim3(16, 16), 256, 0, stream>>>((const ushort_t*)tmpo, (ushort_t*)wTo,
                                                  1024, 1024);
  gemm_bf16<<<dim3(12, 64), 512, 0, stream>>>(xb, 1024, wTq, qkv, 3072, 1024, nullptr);
  transpose_v<<<dim3(64, 64), 256, 0, stream>>>((const ushort_t*)qkv, (ushort_t*)vTb);
  attn_swa<<<dim3(4096), 256, 0, stream>>>(qkv, vTb);
  gemm_bf16<<<dim3(4, 64), 512, 0, stream>>>(qkv, 3072, wTo, d_out, 1024, 1024, flag);
}

// Round 2
// 365.131 us; speedup vs baseline: 1.1982x; 1.0413x over previous
//
#include <hip/hip_runtime.h>

typedef __bf16 bf16_t;
typedef __bf16 bf16x8 __attribute__((ext_vector_type(8)));
typedef float f32x4 __attribute__((ext_vector_type(4)));
typedef unsigned short ushort_t;

#define MFMA_16x16x32(a, b, c) __builtin_amdgcn_mfma_f32_16x16x32_bf16((a), (b), (c), 0, 0, 0)

// async global->LDS, 16B per lane. LDS dest must be wave-uniform; HW adds lane*16.
__device__ __forceinline__ void async_ld16(const void* gptr, void* lptr) {
  typedef __attribute__((address_space(1))) const unsigned int as1_t;
  typedef __attribute__((address_space(3))) unsigned int as3_t;
  __builtin_amdgcn_global_load_lds((as1_t*)(unsigned long long)gptr,
                                   (as3_t*)(unsigned int)(unsigned long long)lptr,
                                   16, 0, 0);
}

// ---------------------------------------------------------------------------
// Input-dtype detector (f32-read-as-bf16 has ~47% wild exponents in low halves).
// ---------------------------------------------------------------------------
__global__ void detect_dtype(const ushort_t* __restrict__ x, int* __restrict__ flag) {
  __shared__ int cnt[256];
  int c = 0;
#pragma unroll
  for (int i = 0; i < 16; ++i) {
    const ushort_t u = x[threadIdx.x * 16 + i];
    const int e = (u >> 7) & 0xFF;
    if ((u & 0x7FFF) != 0 && (e < 0x3A || e > 0xC0)) ++c;
  }
  cnt[threadIdx.x] = c;
  __syncthreads();
  if (threadIdx.x == 0) {
    int t = 0;
    for (int i = 0; i < 256; ++i) t += cnt[i];
    *flag = (t > 512) ? 1 : 0;
  }
}

// ---------------------------------------------------------------------------
// Normalize input to bf16 (flag==1: f32 src; else 16B copy). n8 = elems/8.
// ---------------------------------------------------------------------------
__global__ __launch_bounds__(256) void convert_to_bf16(const void* __restrict__ src,
                                                       bf16_t* __restrict__ dst, int n8,
                                                       const int* __restrict__ flag) {
  const int isF32 = *flag;
  int i = blockIdx.x * 256 + threadIdx.x;
  const int stride = gridDim.x * 256;
  if (isF32) {
    const float4* s = (const float4*)src;
    for (; i < n8; i += stride) {
      const float4 a = s[(size_t)i * 2];
      const float4 b = s[(size_t)i * 2 + 1];
      bf16x8 o;
      o[0] = (bf16_t)a.x; o[1] = (bf16_t)a.y; o[2] = (bf16_t)a.z; o[3] = (bf16_t)a.w;
      o[4] = (bf16_t)b.x; o[5] = (bf16_t)b.y; o[6] = (bf16_t)b.z; o[7] = (bf16_t)b.w;
      *(bf16x8*)(dst + (size_t)i * 8) = o;
    }
  } else {
    const uint4* s = (const uint4*)src;
    for (; i < n8; i += stride) ((uint4*)dst)[i] = s[i];
  }
}

// ---------------------------------------------------------------------------
// 64x64 bf16 transpose: out[c][r] = in[r][c].  R,C multiples of 64.
// ---------------------------------------------------------------------------
__global__ __launch_bounds__(256) void transpose_b16(const ushort_t* __restrict__ in,
                                                     ushort_t* __restrict__ out,
                                                     int R, int C) {
  __shared__ alignas(16) ushort_t t[64 * 72];
  const int tid = threadIdx.x;
  const int c0 = blockIdx.x * 64;
  const int r0 = blockIdx.y * 64;
#pragma unroll
  for (int it = 0; it < 2; ++it) {
    int cid = tid + it * 256;
    int row = cid >> 3, co = (cid & 7) * 8;
    *(uint4*)(t + row * 72 + co) = *(const uint4*)(in + (size_t)(r0 + row) * C + c0 + co);
  }
  __syncthreads();
#pragma unroll
  for (int it = 0; it < 2; ++it) {
    int cid = tid + it * 256;
    int orow = cid >> 3, ko = (cid & 7) * 8;
    uint4 u;
    ushort_t* tp = (ushort_t*)&u;
#pragma unroll
    for (int j = 0; j < 8; ++j) tp[j] = t[(ko + j) * 72 + orow];
    *(uint4*)(out + (size_t)(c0 + orow) * R + r0 + ko) = u;
  }
}

// ---------------------------------------------------------------------------
// Batched V transpose: qkv[b*4096+l][2048+h*64+d] -> vT[((b*16+h)*64+d)*4096+l]
// grid (64 l-tiles, 64 bh). Fully coalesced 16B both sides.
// ---------------------------------------------------------------------------
__global__ __launch_bounds__(256) void transpose_v(const ushort_t* __restrict__ qkv,
                                                   ushort_t* __restrict__ vT) {
  __shared__ alignas(16) ushort_t t[64 * 72];
  const int tid = threadIdx.x;
  const int l0 = blockIdx.x * 64;
  const int bh = blockIdx.y;
  const int b = bh >> 4, h = bh & 15;
  const ushort_t* src = qkv + ((size_t)(b * 4096 + l0)) * 3072 + 2048 + h * 64;
#pragma unroll
  for (int it = 0; it < 2; ++it) {
    int cid = tid + it * 256;
    int row = cid >> 3, co = (cid & 7) * 8;
    *(uint4*)(t + row * 72 + co) = *(const uint4*)(src + (size_t)row * 3072 + co);
  }
  __syncthreads();
  ushort_t* dst = vT + ((size_t)bh * 64) * 4096 + l0;
#pragma unroll
  for (int it = 0; it < 2; ++it) {
    int cid = tid + it * 256;
    int d = cid >> 3, ko = (cid & 7) * 8;
    uint4 u;
    ushort_t* tp = (ushort_t*)&u;
#pragma unroll
    for (int j = 0; j < 8; ++j) tp[j] = t[(ko + j) * 72 + d];
    *(uint4*)(dst + (size_t)d * 4096 + ko) = u;
  }
}

// ---------------------------------------------------------------------------
// GEMM: C[M][N] = A[M][K] * Bt[N][K]^T.  256x256 tile, BK=64, 8 waves (2Mx4N),
// 512 threads, 8-phase schedule (T1+T2+T3+T4+T5).
// vmcnt ledger v2 (waits protect the NEXT phase's ds_reads; FIFO order of
// stage issue per wave, 2 loads/half-tile: P1:A-lo(t+1) P2:B-lo P3:B-hi P4:A-hi):
//   P1 wait(4): drains B-hi(t)   [issued P3(t-1), 3-phase lead] -> P2 reads
//   P2 wait(4): drains A-hi(t)   [issued P4(t-1), 3-phase lead] -> P3 reads
//   P3 no wait: P4 reads nothing from LDS (both B halves held in regs)
//   P4 wait(6): drains A-lo,B-lo(t+1) [issued P1/P2(t), 3-phase lead] -> next P1
// Never waits on a load younger than 3 phases (the R1 ledger stalled at P4 on a
// 1-phase-old load every tile). Last tile stages nothing (vmcnt with fewer
// outstanding loads is a no-op, so the ledger still holds).
// LDS swizzle: linear dest (global_load_lds requires it) + inverse-swizzled
// global source chunk (j ^ (row&7)) + same XOR on ds_read.
// ---------------------------------------------------------------------------
__global__ __launch_bounds__(512) void gemm_bf16(const bf16_t* __restrict__ A, int lda,
                                                 const bf16_t* __restrict__ Bt,
                                                 void* __restrict__ Cout, int N_out,
                                                 int K, const int* __restrict__ flag) {
  __shared__ alignas(16) bf16_t smem[65536];  // 128 KiB: [buf][A 16K | B 16K] elems
  const int tid = threadIdx.x;
  const int wave = tid >> 6;
  const int lane = tid & 63;
  const int l15 = lane & 15;
  const int quad = lane >> 4;
  const int wm = wave >> 2;  // 0..1
  const int wn = wave & 3;   // 0..3

  // XCD-bijective block swizzle (T1); our launches have nwg % 8 == 0.
  int lin = blockIdx.y * gridDim.x + blockIdx.x;
  const int nwg = gridDim.x * gridDim.y;
  if ((nwg & 7) == 0) lin = (lin & 7) * (nwg >> 3) + (lin >> 3);
  const int tn = (lin % gridDim.x) * 256;
  const int tm = (lin / gridDim.x) * 256;

  f32x4 acc[8][4];
#pragma unroll
  for (int i = 0; i < 8; ++i)
#pragma unroll
    for (int j = 0; j < 4; ++j) acc[i][j] = (f32x4){0.f, 0.f, 0.f, 0.f};

  // staging: thread t covers (row = t>>3, chunk = t&7) of a 64-row call-block;
  // global chunk is pre-swizzled so linear LDS ends up XOR-swizzled.
  const int r_st = tid >> 3;
  const int jg8 = ((tid & 7) ^ (r_st & 7)) * 8;
  const int wofs = wave * 512;  // wave-uniform LDS base (elems); HW adds lane*16B

  // fragment-read constants; chunk' = (ks*4|quad) ^ (row&7), row&7 == l15&7
  const int rowA = wm * 16 + l15;
  const int rowB = wn * 16 + l15;
  const int sw = l15 & 7;
  const int c0 = (quad ^ sw) * 8;
  const int c1 = ((quad | 4) ^ sw) * 8;

  const int NT = K >> 6;

#define STAGE_HALF(G, ldg, grow0, kk, ldsbase)                              \
  do {                                                                      \
    const bf16_t* _g = (G) + (size_t)((grow0) + r_st) * (ldg) + (kk) + jg8; \
    async_ld16(_g, &smem[(ldsbase) + wofs]);                                \
    async_ld16(_g + (size_t)64 * (ldg), &smem[(ldsbase) + 4096 + wofs]);    \
  } while (0)

#define READ_A(mh)                                                \
  do {                                                            \
    _Pragma("unroll") for (int q = 0; q < 4; ++q) {               \
      const int off = bufA + (((mh)*128 + q * 32 + rowA) << 6);   \
      a_[q][0] = *(const bf16x8*)&smem[off + c0];                 \
      a_[q][1] = *(const bf16x8*)&smem[off + c1];                 \
    }                                                             \
  } while (0)

#define READ_B(nh, dst)                                           \
  do {                                                            \
    _Pragma("unroll") for (int jn = 0; jn < 2; ++jn) {            \
      const int off = bufB + (((nh)*128 + jn * 64 + rowB) << 6);  \
      dst[jn][0] = *(const bf16x8*)&smem[off + c0];               \
      dst[jn][1] = *(const bf16x8*)&smem[off + c1];               \
    }                                                             \
  } while (0)

#define DO_MFMA(mh, nh, bb)                                                  \
  do {                                                                       \
    _Pragma("unroll") for (int q = 0; q < 4; ++q)                            \
        _Pragma("unroll") for (int jn = 0; jn < 2; ++jn) {                   \
      acc[(mh)*4 + q][(nh)*2 + jn] =                                         \
          MFMA_16x16x32(a_[q][0], bb[jn][0], acc[(mh)*4 + q][(nh)*2 + jn]);  \
      acc[(mh)*4 + q][(nh)*2 + jn] =                                         \
          MFMA_16x16x32(a_[q][1], bb[jn][1], acc[(mh)*4 + q][(nh)*2 + jn]);  \
    }                                                                        \
  } while (0)

#define PHASE_MID(VMC)                                     \
  asm volatile("s_waitcnt vmcnt(" VMC ")" ::: "memory");   \
  __builtin_amdgcn_s_barrier();                            \
  asm volatile("s_waitcnt lgkmcnt(0)" ::: "memory");       \
  __builtin_amdgcn_sched_barrier(0);                       \
  __builtin_amdgcn_s_setprio(1)

#define PHASE_MID_NV()                                     \
  __builtin_amdgcn_s_barrier();                            \
  asm volatile("s_waitcnt lgkmcnt(0)" ::: "memory");       \
  __builtin_amdgcn_sched_barrier(0);                       \
  __builtin_amdgcn_s_setprio(1)

#define PHASE_END()               \
  __builtin_amdgcn_s_setprio(0);  \
  __builtin_amdgcn_s_barrier();   \
  __builtin_amdgcn_sched_barrier(0)

  // prologue: stage K-tile 0 into buffer 0; wait until A-lo,B-lo resident.
  STAGE_HALF(A, lda, tm, 0, 0);
  STAGE_HALF(Bt, K, tn, 0, 16384);
  STAGE_HALF(Bt, K, tn + 128, 0, 16384 + 8192);
  STAGE_HALF(A, lda, tm + 128, 0, 8192);
  asm volatile("s_waitcnt vmcnt(4)" ::: "memory");
  __builtin_amdgcn_s_barrier();

  bf16x8 a_[4][2], b0_[2][2], b1_[2][2];
  int bufA = 0;
  for (int t = 0; t < NT; ++t) {
    const int bufB = bufA + 16384;
    const int sA = bufA ^ 32768;  // stage target = other buffer
    const int sB = sA + 16384;
    const int kst = (t + 1) << 6;
    const bool pf = (kst < K);  // no wrapped prefetch on the last tile

    // P1: quadrant (mh0,nh0); stage A-lo(t+1)
    READ_A(0);
    READ_B(0, b0_);
    if (pf) STAGE_HALF(A, lda, tm, kst, sA);
    PHASE_MID("4");
    DO_MFMA(0, 0, b0_);
    PHASE_END();

    // P2: (mh0,nh1); stage B-lo(t+1)
    READ_B(1, b1_);
    if (pf) STAGE_HALF(Bt, K, tn, kst, sB);
    PHASE_MID("4");
    DO_MFMA(0, 1, b1_);
    PHASE_END();

    // P3: (mh1,nh1); stage B-hi(t+1); no vmcnt (P4 reads nothing from LDS)
    READ_A(1);
    if (pf) STAGE_HALF(Bt, K, tn + 128, kst, sB + 8192);
    PHASE_MID_NV();
    DO_MFMA(1, 1, b1_);
    PHASE_END();

    // P4: (mh1,nh0); stage A-hi(t+1); B-lo still live in b0_
    if (pf) STAGE_HALF(A, lda, tm + 128, kst, sA + 8192);
    PHASE_MID("6");
    DO_MFMA(1, 0, b0_);
    PHASE_END();

    bufA ^= 32768;
  }

  // drain any stragglers before reusing smem for the epilogue.
  asm volatile("s_waitcnt vmcnt(0)" ::: "memory");
  __syncthreads();

  const int isF32 = flag ? *flag : 0;
  if (isF32) {
#pragma unroll
    for (int f = 0; f < 8; ++f) {
      const int m0 = tm + (f >> 2) * 128 + (f & 3) * 32 + wm * 16 + quad * 4;
#pragma unroll
      for (int nidx = 0; nidx < 4; ++nidx) {
        const int col = tn + (nidx >> 1) * 128 + (nidx & 1) * 64 + wn * 16 + l15;
        float* cp = (float*)Cout + (size_t)m0 * N_out + col;
#pragma unroll
        for (int r = 0; r < 4; ++r) cp[(size_t)r * N_out] = acc[f][nidx][r];
      }
    }
  } else {
    // per-wave 16x72 staging tile; shuffle C-layout -> 16B/lane coalesced stores
    bf16_t* stg = smem + wave * 1152;
#pragma unroll
    for (int f = 0; f < 8; ++f) {
#pragma unroll
      for (int nidx = 0; nidx < 4; ++nidx)
#pragma unroll
        for (int r = 0; r < 4; ++r)
          stg[(quad * 4 + r) * 72 + nidx * 16 + l15] = (bf16_t)acc[f][nidx][r];
      __asm__ volatile("s_waitcnt lgkmcnt(0)" ::: "memory");
      const int m0 = tm + (f >> 2) * 128 + (f & 3) * 32 + wm * 16;
#pragma unroll
      for (int p = 0; p < 2; ++p) {
        const int idx = lane + p * 64;
        const int row = idx >> 3, c8 = (idx & 7) * 8;
        uint4 u = *(const uint4*)(stg + row * 72 + c8);
        const int col = tn + ((c8 >> 5) << 7) + (((c8 >> 4) & 1) << 6) + wn * 16 + (c8 & 15);
        *(uint4*)((bf16_t*)Cout + (size_t)(m0 + row) * N_out + col) = u;
      }
      __asm__ volatile("s_waitcnt lgkmcnt(0)" ::: "memory");
    }
  }
#undef STAGE_HALF
#undef READ_A
#undef READ_B
#undef DO_MFMA
#undef PHASE_MID
#undef PHASE_MID_NV
#undef PHASE_END
}

// ---------------------------------------------------------------------------
// Sliding-window attention. One workgroup = 64 queries of one (b,h); 4 waves x
// 16 rows. Window = 5 chunks of 64 keys. qkv: [b*4096+pos][3072] (Q at h*64,
// K at 1024+h*64; O overwrites the Q columns). vT: [b][h][d][4096].
// R2: T14 reg-prefetch of next chunk's K/V (loads fly under current chunk's
// QK+softmax+PV), 2 barriers/chunk (p_lds is wave-private -> no 3rd barrier),
// T5 setprio around MFMA clusters, XCD swizzle for (b,h) K/V L2 locality.
// ---------------------------------------------------------------------------
__global__ __launch_bounds__(256) void attn_swa(bf16_t* qkv, const bf16_t* __restrict__ vT) {
  __shared__ alignas(16) bf16_t k_lds[64 * 72];   // [key][d]
  __shared__ alignas(16) bf16_t vt_lds[64 * 72];  // [d][key]
  __shared__ alignas(16) bf16_t p_lds[4 * 16 * 72];

  // XCD swizzle: 512 consecutive logical wgs (8 (b,h) pairs) per XCD.
  int wg = blockIdx.x;
  wg = (wg & 7) * 512 + (wg >> 3);
  const int b = wg >> 10;
  const int h = (wg >> 6) & 15;
  const int qt = wg & 63;
  const int blk = qt >> 2;
  const int wq = qt & 3;
  const int tid = threadIdx.x;
  const int wave = tid >> 6;
  const int lane = tid & 63;
  const int l15 = lane & 15;
  const int quad = lane >> 4;
  const int qw = qt * 64 + wave * 16;

  const size_t qoff = ((size_t)(b * 4096 + qw + l15)) * 3072 + h * 64;
  const bf16x8 qf0 = *(const bf16x8*)(qkv + qoff + quad * 8);
  const bf16x8 qf1 = *(const bf16x8*)(qkv + qoff + 32 + quad * 8);

  f32x4 of[4];
#pragma unroll
  for (int i = 0; i < 4; ++i) of[i] = (f32x4){0.f, 0.f, 0.f, 0.f};
  float m_i[4], l_i[4];
#pragma unroll
  for (int r = 0; r < 4; ++r) {
    m_i[r] = -1e30f;
    l_i[r] = 0.0f;
  }

  const int kb0 = blk * 256 - 256;
  const int kclo = (blk == 0) ? 4 : wq;
  const int kchi = wq + 4;

  // T14 staging regs: thread covers rows {row0, row0+32}, 16B col chunk co8.
  const int row0 = tid >> 3;
  const int co8 = (tid & 7) * 8;
  const bf16_t* kbase = qkv + ((size_t)b * 4096) * 3072 + 1024 + h * 64;
  const bf16_t* vbase = vT + (((size_t)b * 16 + h) * 64) * 4096;
  uint4 kr0, kr1, vr0, vr1;

#define ISSUE_KV(KB)                                                           \
  do {                                                                         \
    kr0 = *(const uint4*)(kbase + (size_t)((KB) + row0) * 3072 + co8);         \
    kr1 = *(const uint4*)(kbase + (size_t)((KB) + row0 + 32) * 3072 + co8);    \
    vr0 = *(const uint4*)(vbase + (size_t)row0 * 4096 + (KB) + co8);           \
    vr1 = *(const uint4*)(vbase + (size_t)(row0 + 32) * 4096 + (KB) + co8);    \
  } while (0)

  ISSUE_KV(kb0 + kclo * 64);

  for (int kc = kclo; kc <= kchi; ++kc) {
    const int kb = kb0 + kc * 64;
    __syncthreads();  // prev chunk's PV reads done -> LDS reusable
    *(uint4*)(k_lds + row0 * 72 + co8) = kr0;
    *(uint4*)(k_lds + (row0 + 32) * 72 + co8) = kr1;
    *(uint4*)(vt_lds + row0 * 72 + co8) = vr0;
    *(uint4*)(vt_lds + (row0 + 32) * 72 + co8) = vr1;
    if (kc < kchi) ISSUE_KV(kb + 64);  // in flight under QK+softmax+PV
    __syncthreads();

    f32x4 s[4];
    __builtin_amdgcn_s_setprio(1);
#pragma unroll
    for (int nt = 0; nt < 4; ++nt) {
      bf16x8 kf0 = *(const bf16x8*)(k_lds + (nt * 16 + l15) * 72 + quad * 8);
      bf16x8 kf1 = *(const bf16x8*)(k_lds + (nt * 16 + l15) * 72 + 32 + quad * 8);
      f32x4 z = (f32x4){0.f, 0.f, 0.f, 0.f};
      z = MFMA_16x16x32(qf0, kf0, z);
      z = MFMA_16x16x32(qf1, kf1, z);
      s[nt] = z;
    }
    __builtin_amdgcn_s_setprio(0);

    float sv[4][4];
#pragma unroll
    for (int nt = 0; nt < 4; ++nt) {
      const int key = kb + nt * 16 + l15;
#pragma unroll
      for (int r = 0; r < 4; ++r) {
        const int p = qw + quad * 4 + r;
        const bool valid = (key <= p) && (key + 256 > p);
        sv[nt][r] = valid ? s[nt][r] * 0.125f : -1e30f;
      }
    }
    float rm[4];
#pragma unroll
    for (int r = 0; r < 4; ++r)
      rm[r] = fmaxf(fmaxf(sv[0][r], sv[1][r]), fmaxf(sv[2][r], sv[3][r]));
#pragma unroll
    for (int off = 1; off < 16; off <<= 1)
#pragma unroll
      for (int r = 0; r < 4; ++r) rm[r] = fmaxf(rm[r], __shfl_xor(rm[r], off));

    float mn[4], alpha[4];
#pragma unroll
    for (int r = 0; r < 4; ++r) {
      mn[r] = fmaxf(m_i[r], rm[r]);
      alpha[r] = __expf(m_i[r] - mn[r]);
      m_i[r] = mn[r];
    }

    float rs[4] = {0.f, 0.f, 0.f, 0.f};
#pragma unroll
    for (int nt = 0; nt < 4; ++nt)
#pragma unroll
      for (int r = 0; r < 4; ++r) {
        const float pv = (sv[nt][r] > -1e29f) ? __expf(sv[nt][r] - mn[r]) : 0.0f;
        rs[r] += pv;
        p_lds[wave * 1152 + (quad * 4 + r) * 72 + nt * 16 + l15] = (bf16_t)pv;
      }
#pragma unroll
    for (int off = 1; off < 16; off <<= 1)
#pragma unroll
      for (int r = 0; r < 4; ++r) rs[r] += __shfl_xor(rs[r], off);
#pragma unroll
    for (int r = 0; r < 4; ++r) l_i[r] = l_i[r] * alpha[r] + rs[r];
#pragma unroll
    for (int dt = 0; dt < 4; ++dt)
#pragma unroll
      for (int r = 0; r < 4; ++r) of[dt][r] *= alpha[r];

    // p_lds slice is wave-private (write->read same wave, lgkmcnt-ordered);
    // vt_lds was made visible by the post-staging barrier. No barrier here.
    __builtin_amdgcn_s_setprio(1);
#pragma unroll
    for (int kk = 0; kk < 2; ++kk) {
      bf16x8 pf = *(const bf16x8*)(p_lds + wave * 1152 + l15 * 72 + kk * 32 + quad * 8);
#pragma unroll
      for (int dt = 0; dt < 4; ++dt) {
        bf16x8 vf = *(const bf16x8*)(vt_lds + (dt * 16 + l15) * 72 + kk * 32 + quad * 8);
        of[dt] = MFMA_16x16x32(pf, vf, of[dt]);
      }
    }
    __builtin_amdgcn_s_setprio(0);
  }
#undef ISSUE_KV

  float inv[4];
#pragma unroll
  for (int r = 0; r < 4; ++r) inv[r] = 1.0f / fmaxf(l_i[r], 1e-20f);
  bf16_t* op = qkv + ((size_t)(b * 4096 + qw)) * 3072 + h * 64;  // overwrite Q cols
#pragma unroll
  for (int dt = 0; dt < 4; ++dt)
#pragma unroll
    for (int r = 0; r < 4; ++r)
      op[(size_t)(quad * 4 + r) * 3072 + dt * 16 + l15] = (bf16_t)(of[dt][r] * inv[r]);
}

// ---------------------------------------------------------------------------
extern "C" void kernel_launch(void* const* d_in, const int* in_sizes, int n_in,
                              void* d_out, int out_size, void* d_ws, size_t ws_size,
                              hipStream_t stream) {
  char* ws = (char*)d_ws;
  bf16_t* wTq = (bf16_t*)(ws);                    // [3072][1024]   6,291,456 B
  bf16_t* wTo = (bf16_t*)(ws + 6291456);          // [1024][1024]   2,097,152 B
  bf16_t* qkv = (bf16_t*)(ws + 8388608);          // [16384][3072] 100,663,296 B
  int* flag = (int*)(ws + 109051904);             // 4 B (total 109,051,908 B)

  bf16_t* xb = (bf16_t*)d_out;   // converted x (32 MB), consumed by QKV GEMM
  bf16_t* vTb = (bf16_t*)d_out;  // then vT (32 MB), consumed by attention,
                                 // then final GEMM writes d_out. Stream-ordered.
  bf16_t* tmpq = qkv;            // converted w_qkv, consumed by transpose
  bf16_t* tmpo = qkv + 3145728;  // converted w_out, consumed by transpose

  detect_dtype<<<1, 256, 0, stream>>>((const ushort_t*)d_in[0], flag);
  convert_to_bf16<<<1024, 256, 0, stream>>>(d_in[0], xb, 2097152, flag);
  convert_to_bf16<<<512, 256, 0, stream>>>(d_in[1], tmpq, 393216, flag);
  convert_to_bf16<<<256, 256, 0, stream>>>(d_in[2], tmpo, 131072, flag);
  transpose_b16<<<dim3(48, 16), 256, 0, stream>>>((const ushort_t*)tmpq, (ushort_t*)wTq,
                                                  1024, 3072);
  transpose_b16<<<dim3(16, 16), 256, 0, stream>>>((const ushort_t*)tmpo, (ushort_t*)wTo,
                                                  1024, 1024);
  gemm_bf16<<<dim3(12, 64), 512, 0, stream>>>(xb, 1024, wTq, qkv, 3072, 1024, nullptr);
  transpose_v<<<dim3(64, 64), 256, 0, stream>>>((const ushort_t*)qkv, (ushort_t*)vTb);
  attn_swa<<<dim3(4096), 256, 0, stream>>>(qkv, vTb);
  gemm_bf16<<<dim3(4, 64), 512, 0, stream>>>(qkv, 3072, wTo, d_out, 1024, 1024, flag);
}